// Round 1
// baseline (90.916 us; speedup 1.0000x reference)
//
#include <hip/hip_runtime.h>

constexpr int BB = 8, CC = 512, TT = 8192;
static_assert((TT & (TT - 1)) == 0 && (CC & (CC - 1)) == 0, "pow2");
constexpr int LOG_T = 13, LOG_C = 9;
constexpr float MOM = 0.05f, EPSV = 1e-6f;

// ---------------- kernel 1: softmax over C for Wa_w and Wb_w ----------------
__global__ __launch_bounds__(512) void k_softmax(const float* __restrict__ Wa,
                                                 const float* __restrict__ Wb,
                                                 float* __restrict__ wa,
                                                 float* __restrict__ wb) {
  __shared__ float red[512];
  const int tid = threadIdx.x;

  // --- Wa ---
  float v = Wa[tid];
  red[tid] = v; __syncthreads();
  for (int off = 256; off > 0; off >>= 1) {
    if (tid < off) red[tid] = fmaxf(red[tid], red[tid + off]);
    __syncthreads();
  }
  float mx = red[0]; __syncthreads();
  float e = expf(v - mx);
  red[tid] = e; __syncthreads();
  for (int off = 256; off > 0; off >>= 1) {
    if (tid < off) red[tid] += red[tid + off];
    __syncthreads();
  }
  wa[tid] = e / red[0];
  __syncthreads();

  // --- Wb ---
  v = Wb[tid];
  red[tid] = v; __syncthreads();
  for (int off = 256; off > 0; off >>= 1) {
    if (tid < off) red[tid] = fmaxf(red[tid], red[tid + off]);
    __syncthreads();
  }
  mx = red[0]; __syncthreads();
  e = expf(v - mx);
  red[tid] = e; __syncthreads();
  for (int off = 256; off > 0; off >>= 1) {
    if (tid < off) red[tid] += red[tid + off];
    __syncthreads();
  }
  wb[tid] = e / red[0];
}

// ------- kernel 2: per (b,t) weighted reductions over C: sa, sb, sb2 -------
// block = 256 threads = 4 waves; wave cp covers channels [cp*128, cp*128+128)
// lane l covers t = tbase + 4*l .. +3 (float4). 1 KiB/wave/iteration, coalesced.
__global__ __launch_bounds__(256) void k_reduce_c(const float* __restrict__ x,
                                                  const float* __restrict__ wa,
                                                  const float* __restrict__ wb,
                                                  float* __restrict__ sa,
                                                  float* __restrict__ sb,
                                                  float* __restrict__ sb2) {
  __shared__ float lwa[CC];
  __shared__ float lwb[CC];
  __shared__ float red[3][4][256];
  const int tid = threadIdx.x;
  lwa[tid] = wa[tid]; lwa[tid + 256] = wa[tid + 256];
  lwb[tid] = wb[tid]; lwb[tid + 256] = wb[tid + 256];
  __syncthreads();

  const int tilesPerB = TT / 256;  // 32
  const int b = blockIdx.x / tilesPerB;
  const int tbase = (blockIdx.x % tilesPerB) * 256;
  const int l = tid & 63;
  const int cp = tid >> 6;
  const int t = tbase + l * 4;
  const float* xp = x + ((size_t)(b * CC + cp * 128)) * TT + t;

  float a0=0,a1=0,a2=0,a3=0;
  float b0=0,b1=0,b2=0,b3=0;
  float q0=0,q1=0,q2=0,q3=0;
  const int cbase = cp * 128;
  #pragma unroll 4
  for (int cc = 0; cc < 128; ++cc) {
    float4 xv = *(const float4*)(xp + (size_t)cc * TT);
    float wac = lwa[cbase + cc];
    float wbc = lwb[cbase + cc];
    a0 = fmaf(wac, xv.x, a0); a1 = fmaf(wac, xv.y, a1);
    a2 = fmaf(wac, xv.z, a2); a3 = fmaf(wac, xv.w, a3);
    b0 = fmaf(wbc, xv.x, b0); b1 = fmaf(wbc, xv.y, b1);
    b2 = fmaf(wbc, xv.z, b2); b3 = fmaf(wbc, xv.w, b3);
    q0 = fmaf(wbc * xv.x, xv.x, q0); q1 = fmaf(wbc * xv.y, xv.y, q1);
    q2 = fmaf(wbc * xv.z, xv.z, q2); q3 = fmaf(wbc * xv.w, xv.w, q3);
  }
  const int li = l * 4;
  red[0][cp][li+0]=a0; red[0][cp][li+1]=a1; red[0][cp][li+2]=a2; red[0][cp][li+3]=a3;
  red[1][cp][li+0]=b0; red[1][cp][li+1]=b1; red[1][cp][li+2]=b2; red[1][cp][li+3]=b3;
  red[2][cp][li+0]=q0; red[2][cp][li+1]=q1; red[2][cp][li+2]=q2; red[2][cp][li+3]=q3;
  __syncthreads();

  if (tid < 64) {
    const int o = tid * 4;
    float oa[4], ob[4], oq[4];
    #pragma unroll
    for (int k = 0; k < 4; ++k) {
      oa[k] = red[0][0][o+k] + red[0][1][o+k] + red[0][2][o+k] + red[0][3][o+k];
      ob[k] = red[1][0][o+k] + red[1][1][o+k] + red[1][2][o+k] + red[1][3][o+k];
      oq[k] = red[2][0][o+k] + red[2][1][o+k] + red[2][2][o+k] + red[2][3][o+k];
    }
    const size_t dst = (size_t)b * TT + tbase + o;
    *(float4*)(sa  + dst) = make_float4(oa[0], oa[1], oa[2], oa[3]);
    *(float4*)(sb  + dst) = make_float4(ob[0], ob[1], ob[2], ob[3]);
    *(float4*)(sb2 + dst) = make_float4(oq[0], oq[1], oq[2], oq[3]);
  }
}

// ---------------- kernel 3: per-batch gated-EMA scans over T ----------------
// y[t] = (1-g)y[t-1] + g*in[t] is an affine map; compose per 32-step chunk,
// Hillis-Steele scan of (A,B) pairs over 256 threads, then replay chunk.
__device__ __forceinline__ float affine_scan_prev(float A, float Bv, float* As,
                                                  float* Bs, int tid) {
  __syncthreads();             // protect previous contents still being read
  As[tid] = A; Bs[tid] = Bv;
  __syncthreads();
  for (int off = 1; off < 256; off <<= 1) {
    float cA = As[tid], cB = Bs[tid];
    float pA = 1.f, pB = 0.f;
    if (tid >= off) { pA = As[tid - off]; pB = Bs[tid - off]; }
    __syncthreads();
    if (tid >= off) { As[tid] = cA * pA; Bs[tid] = fmaf(cA, pB, cB); }
    __syncthreads();
  }
  // exclusive prefix applied to y0 = 0  ->  just the B term
  return (tid == 0) ? 0.f : Bs[tid - 1];
}

__global__ __launch_bounds__(256) void k_scan(const float* __restrict__ g,
                                              const float* __restrict__ sa,
                                              const float* __restrict__ sb,
                                              const float* __restrict__ sb2,
                                              float* __restrict__ mean,
                                              float* __restrict__ inv) {
  constexpr int CH = TT / 256;  // 32 timesteps per thread
  __shared__ float As[256], Bs[256];
  const int tid = threadIdx.x;
  const size_t base = (size_t)blockIdx.x * TT + (size_t)tid * CH;

  float gt[CH], pa[CH], mv[CH], vin[CH];

  // mean EMA: compose chunk
  float A = 1.f, Bv = 0.f;
  #pragma unroll
  for (int j = 0; j < CH; ++j) {
    float gg = g[base + j] * MOM;
    gt[j] = gg;
    pa[j] = gg * sa[base + j];
    float a = 1.f - gg;
    A *= a;
    Bv = fmaf(a, Bv, pa[j]);
  }
  float m = affine_scan_prev(A, Bv, As, Bs, tid);
  #pragma unroll
  for (int j = 0; j < CH; ++j) {
    m = fmaf(1.f - gt[j], m, pa[j]);
    mv[j] = m;
    mean[base + j] = m;
  }

  // var EMA: input = sb2 - 2*m*sb + m^2  (uses sum(wb)=1)
  float A2 = 1.f, B2 = 0.f;
  #pragma unroll
  for (int j = 0; j < CH; ++j) {
    float sbv = sb[base + j], s2v = sb2[base + j];
    float vi = fmaf(mv[j], mv[j], fmaf(-2.f * mv[j], sbv, s2v));
    vin[j] = vi;
    float a = 1.f - gt[j];
    A2 *= a;
    B2 = fmaf(a, B2, gt[j] * vi);
  }
  float v = affine_scan_prev(A2, B2, As, Bs, tid);
  #pragma unroll
  for (int j = 0; j < CH; ++j) {
    v = fmaf(1.f - gt[j], v, gt[j] * vin[j]);
    inv[base + j] = rsqrtf(v + EPSV);
  }
}

// ---------------- kernel 4: pointwise output ----------------
__global__ __launch_bounds__(256) void k_out(const float* __restrict__ x,
                                             const float* __restrict__ mean,
                                             const float* __restrict__ inv,
                                             const float* __restrict__ wo,
                                             const float* __restrict__ bo,
                                             float* __restrict__ out) {
  const size_t n4 = (size_t)BB * CC * TT / 4;
  const size_t stride = (size_t)gridDim.x * blockDim.x;
  for (size_t i = (size_t)blockIdx.x * blockDim.x + threadIdx.x; i < n4; i += stride) {
    const size_t flat = i * 4;
    const int t = (int)(flat & (TT - 1));
    const size_t rem = flat >> LOG_T;
    const int c = (int)(rem & (CC - 1));
    const int b = (int)(rem >> LOG_C);
    float4 xv = *(const float4*)(x + flat);
    const size_t mi = ((size_t)b << LOG_T) + t;
    float4 m4 = *(const float4*)(mean + mi);
    float4 i4 = *(const float4*)(inv + mi);
    const float w = wo[c], bb = bo[c];
    float4 o;
    o.x = fmaf((xv.x - m4.x) * i4.x, w, bb);
    o.y = fmaf((xv.y - m4.y) * i4.y, w, bb);
    o.z = fmaf((xv.z - m4.z) * i4.z, w, bb);
    o.w = fmaf((xv.w - m4.w) * i4.w, w, bb);
    *(float4*)(out + flat) = o;
  }
}

extern "C" void kernel_launch(void* const* d_in, const int* in_sizes, int n_in,
                              void* d_out, int out_size, void* d_ws, size_t ws_size,
                              hipStream_t stream) {
  const float* x    = (const float*)d_in[0];  // (B, C, T)
  const float* g    = (const float*)d_in[1];  // (B, 1, T)
  const float* Wa_w = (const float*)d_in[2];  // (1, C, 1)
  const float* Wb_w = (const float*)d_in[3];  // (1, C, 1)
  const float* Wo_w = (const float*)d_in[4];  // (C, 1, 1)
  const float* Wo_b = (const float*)d_in[5];  // (C,)
  float* out = (float*)d_out;

  constexpr int BT = BB * TT;
  float* ws   = (float*)d_ws;
  float* wa   = ws;               // C
  float* wb   = ws + CC;          // C
  float* sa   = ws + 2 * CC;      // B*T
  float* sb   = sa + BT;          // B*T
  float* sb2  = sb + BT;          // B*T
  float* mean = sb2 + BT;         // B*T
  float* inv  = mean + BT;        // B*T  (total ~1.26 MiB)

  k_softmax<<<1, 512, 0, stream>>>(Wa_w, Wb_w, wa, wb);
  k_reduce_c<<<BB * (TT / 256), 256, 0, stream>>>(x, wa, wb, sa, sb, sb2);
  k_scan<<<BB, 256, 0, stream>>>(g, sa, sb, sb2, mean, inv);
  k_out<<<2048, 256, 0, stream>>>(x, mean, inv, Wo_w, Wo_b, out);
}

// Round 2
// 83.127 us; speedup vs baseline: 1.0937x; 1.0937x over previous
//
#include <hip/hip_runtime.h>

constexpr int BB = 8, CC = 512, TT = 8192;
static_assert((TT & (TT - 1)) == 0 && (CC & (CC - 1)) == 0, "pow2");
constexpr int LOG_T = 13, LOG_C = 9;
constexpr float MOM = 0.05f, EPSV = 1e-6f;

typedef float v4f __attribute__((ext_vector_type(4)));

// ------- kernel 1: inline softmax + per (b,t) weighted reductions over C ----
// block = 256 threads = 4 waves; wave wid covers channels [wid*128, wid*128+128)
// lane l covers t = tbase + 4*l .. +3 (float4). 1 KiB/wave/iteration, coalesced.
__global__ __launch_bounds__(256) void k_reduce_c(const float* __restrict__ x,
                                                  const float* __restrict__ Wa,
                                                  const float* __restrict__ Wb,
                                                  float* __restrict__ sa,
                                                  float* __restrict__ sb,
                                                  float* __restrict__ sb2) {
  __shared__ float lwa[CC];
  __shared__ float lwb[CC];
  __shared__ float xw[8];
  __shared__ float red[3][4][256];
  const int tid = threadIdx.x;
  const int lane = tid & 63;
  const int wid = tid >> 6;

  // --- softmax over C for Wa and Wb, computed redundantly per block ---
  float va0 = Wa[tid], va1 = Wa[tid + 256];
  float vb0 = Wb[tid], vb1 = Wb[tid + 256];
  float ma = fmaxf(va0, va1), mb = fmaxf(vb0, vb1);
  #pragma unroll
  for (int off = 32; off > 0; off >>= 1) {
    ma = fmaxf(ma, __shfl_down(ma, off, 64));
    mb = fmaxf(mb, __shfl_down(mb, off, 64));
  }
  if (lane == 0) { xw[wid] = ma; xw[4 + wid] = mb; }
  __syncthreads();
  ma = fmaxf(fmaxf(xw[0], xw[1]), fmaxf(xw[2], xw[3]));
  mb = fmaxf(fmaxf(xw[4], xw[5]), fmaxf(xw[6], xw[7]));
  float ea0 = expf(va0 - ma), ea1 = expf(va1 - ma);
  float eb0 = expf(vb0 - mb), eb1 = expf(vb1 - mb);
  float sA = ea0 + ea1, sB = eb0 + eb1;
  #pragma unroll
  for (int off = 32; off > 0; off >>= 1) {
    sA += __shfl_down(sA, off, 64);
    sB += __shfl_down(sB, off, 64);
  }
  __syncthreads();  // xw about to be reused
  if (lane == 0) { xw[wid] = sA; xw[4 + wid] = sB; }
  __syncthreads();
  sA = xw[0] + xw[1] + xw[2] + xw[3];
  sB = xw[4] + xw[5] + xw[6] + xw[7];
  const float rA = 1.f / sA, rB = 1.f / sB;
  lwa[tid] = ea0 * rA; lwa[tid + 256] = ea1 * rA;
  lwb[tid] = eb0 * rB; lwb[tid + 256] = eb1 * rB;
  __syncthreads();

  // --- main weighted reduction over C ---
  const int tilesPerB = TT / 256;  // 32
  const int b = blockIdx.x / tilesPerB;
  const int tbase = (blockIdx.x % tilesPerB) * 256;
  const int t = tbase + lane * 4;
  const float* xp = x + ((size_t)(b * CC + wid * 128)) * TT + t;

  float a0=0,a1=0,a2=0,a3=0;
  float b0=0,b1=0,b2=0,b3=0;
  float q0=0,q1=0,q2=0,q3=0;
  const int cbase = wid * 128;
  #pragma unroll 4
  for (int cc = 0; cc < 128; ++cc) {
    float4 xv = *(const float4*)(xp + (size_t)cc * TT);
    float wac = lwa[cbase + cc];
    float wbc = lwb[cbase + cc];
    a0 = fmaf(wac, xv.x, a0); a1 = fmaf(wac, xv.y, a1);
    a2 = fmaf(wac, xv.z, a2); a3 = fmaf(wac, xv.w, a3);
    b0 = fmaf(wbc, xv.x, b0); b1 = fmaf(wbc, xv.y, b1);
    b2 = fmaf(wbc, xv.z, b2); b3 = fmaf(wbc, xv.w, b3);
    q0 = fmaf(wbc * xv.x, xv.x, q0); q1 = fmaf(wbc * xv.y, xv.y, q1);
    q2 = fmaf(wbc * xv.z, xv.z, q2); q3 = fmaf(wbc * xv.w, xv.w, q3);
  }
  const int li = lane * 4;
  red[0][wid][li+0]=a0; red[0][wid][li+1]=a1; red[0][wid][li+2]=a2; red[0][wid][li+3]=a3;
  red[1][wid][li+0]=b0; red[1][wid][li+1]=b1; red[1][wid][li+2]=b2; red[1][wid][li+3]=b3;
  red[2][wid][li+0]=q0; red[2][wid][li+1]=q1; red[2][wid][li+2]=q2; red[2][wid][li+3]=q3;
  __syncthreads();

  if (tid < 64) {
    const int o = tid * 4;
    float oa[4], ob[4], oq[4];
    #pragma unroll
    for (int k = 0; k < 4; ++k) {
      oa[k] = red[0][0][o+k] + red[0][1][o+k] + red[0][2][o+k] + red[0][3][o+k];
      ob[k] = red[1][0][o+k] + red[1][1][o+k] + red[1][2][o+k] + red[1][3][o+k];
      oq[k] = red[2][0][o+k] + red[2][1][o+k] + red[2][2][o+k] + red[2][3][o+k];
    }
    const size_t dst = (size_t)b * TT + tbase + o;
    *(float4*)(sa  + dst) = make_float4(oa[0], oa[1], oa[2], oa[3]);
    *(float4*)(sb  + dst) = make_float4(ob[0], ob[1], ob[2], ob[3]);
    *(float4*)(sb2 + dst) = make_float4(oq[0], oq[1], oq[2], oq[3]);
  }
}

// ---------------- kernel 2: per-batch gated-EMA scans over T ----------------
// y[t] = (1-g)y[t-1] + g*in[t] is affine; compose per 32-step chunk, then
// shfl-based wave scan (6 rounds, no barriers) + 4-entry cross-wave fixup.
__device__ __forceinline__ float affine_scan_prev(float A, float B, int tid,
                                                  float* wAs, float* wBs) {
  const int lane = tid & 63;
  const int wid = tid >> 6;
  // inclusive wave scan of affine pairs: self = self ∘ prev
  #pragma unroll
  for (int off = 1; off < 64; off <<= 1) {
    float pA = __shfl_up(A, off, 64);
    float pB = __shfl_up(B, off, 64);
    if (lane >= off) { B = fmaf(A, pB, B); A *= pA; }
  }
  __syncthreads();  // protect scratch from previous call
  if (lane == 63) { wAs[wid] = A; wBs[wid] = B; }
  __syncthreads();
  // carry = composition of full aggregates of waves < wid (in order)
  float cB = 0.f;
  for (int w = 0; w < wid; ++w) cB = fmaf(wAs[w], cB, wBs[w]);
  // lane-exclusive within wave = inclusive of lane-1
  float leA = __shfl_up(A, 1, 64);
  float leB = __shfl_up(B, 1, 64);
  if (lane == 0) { leA = 1.f; leB = 0.f; }
  // prefix = laneExcl ∘ carry, applied to y0 = 0  ->  leA*cB + leB
  return fmaf(leA, cB, leB);
}

__global__ __launch_bounds__(256) void k_scan(const float* __restrict__ g,
                                              const float* __restrict__ sa,
                                              const float* __restrict__ sb,
                                              const float* __restrict__ sb2,
                                              float* __restrict__ mean,
                                              float* __restrict__ inv) {
  constexpr int CH = TT / 256;  // 32 timesteps per thread
  __shared__ float wAs[4], wBs[4];
  const int tid = threadIdx.x;
  const size_t base = (size_t)blockIdx.x * TT + (size_t)tid * CH;

  float gt[CH], pa[CH];

  // pass 1: load g, sa; compose chunk for mean EMA
  float A = 1.f, Bv = 0.f;
  #pragma unroll
  for (int j = 0; j < CH; j += 4) {
    float gv[4]; *(float4*)gv = *(const float4*)(g + base + j);
    float sv[4]; *(float4*)sv = *(const float4*)(sa + base + j);
    #pragma unroll
    for (int k = 0; k < 4; ++k) {
      float gg = gv[k] * MOM;
      gt[j + k] = gg;
      float p = gg * sv[k];
      pa[j + k] = p;
      float a = 1.f - gg;
      A *= a;
      Bv = fmaf(a, Bv, p);
    }
  }
  float m = affine_scan_prev(A, Bv, tid, wAs, wBs);

  // pass 2: replay mean, store; build var-EMA input (folds into pa), compose
  float A2 = 1.f, B2 = 0.f;
  #pragma unroll
  for (int j = 0; j < CH; j += 4) {
    float bv[4]; *(float4*)bv = *(const float4*)(sb  + base + j);
    float qv[4]; *(float4*)qv = *(const float4*)(sb2 + base + j);
    float m4[4];
    #pragma unroll
    for (int k = 0; k < 4; ++k) {
      float a = 1.f - gt[j + k];
      m = fmaf(a, m, pa[j + k]);
      m4[k] = m;
      // vin = sb2 - 2*m*sb + m^2   (uses sum(wb)=1)
      float vi = fmaf(m, m, fmaf(-2.f * m, bv[k], qv[k]));
      float pv = gt[j + k] * vi;
      pa[j + k] = pv;
      A2 *= a;
      B2 = fmaf(a, B2, pv);
    }
    *(float4*)(mean + base + j) = *(float4*)m4;
  }
  float v = affine_scan_prev(A2, B2, tid, wAs, wBs);

  // pass 3: replay var, store inv
  #pragma unroll
  for (int j = 0; j < CH; j += 4) {
    float i4[4];
    #pragma unroll
    for (int k = 0; k < 4; ++k) {
      v = fmaf(1.f - gt[j + k], v, pa[j + k]);
      i4[k] = rsqrtf(v + EPSV);
    }
    *(float4*)(inv + base + j) = *(float4*)i4;
  }
}

// ---------------- kernel 3: pointwise output ----------------
__global__ __launch_bounds__(256) void k_out(const float* __restrict__ x,
                                             const float* __restrict__ mean,
                                             const float* __restrict__ inv,
                                             const float* __restrict__ wo,
                                             const float* __restrict__ bo,
                                             float* __restrict__ out) {
  const size_t n4 = (size_t)BB * CC * TT / 4;
  const size_t stride = (size_t)gridDim.x * blockDim.x;
  for (size_t i = (size_t)blockIdx.x * blockDim.x + threadIdx.x; i < n4; i += stride) {
    const size_t flat = i * 4;
    const int t = (int)(flat & (TT - 1));
    const size_t rem = flat >> LOG_T;
    const int c = (int)(rem & (CC - 1));
    const int b = (int)(rem >> LOG_C);
    float4 xv = *(const float4*)(x + flat);
    const size_t mi = ((size_t)b << LOG_T) + t;
    float4 m4 = *(const float4*)(mean + mi);
    float4 i4 = *(const float4*)(inv + mi);
    const float w = wo[c], bb = bo[c];
    v4f o;
    o.x = fmaf((xv.x - m4.x) * i4.x, w, bb);
    o.y = fmaf((xv.y - m4.y) * i4.y, w, bb);
    o.z = fmaf((xv.z - m4.z) * i4.z, w, bb);
    o.w = fmaf((xv.w - m4.w) * i4.w, w, bb);
    // non-temporal: keep the out stream from evicting L3-resident x
    __builtin_nontemporal_store(o, (v4f*)(out + flat));
  }
}

extern "C" void kernel_launch(void* const* d_in, const int* in_sizes, int n_in,
                              void* d_out, int out_size, void* d_ws, size_t ws_size,
                              hipStream_t stream) {
  const float* x    = (const float*)d_in[0];  // (B, C, T)
  const float* g    = (const float*)d_in[1];  // (B, 1, T)
  const float* Wa_w = (const float*)d_in[2];  // (1, C, 1)
  const float* Wb_w = (const float*)d_in[3];  // (1, C, 1)
  const float* Wo_w = (const float*)d_in[4];  // (C, 1, 1)
  const float* Wo_b = (const float*)d_in[5];  // (C,)
  float* out = (float*)d_out;

  constexpr int BT = BB * TT;
  float* ws   = (float*)d_ws;
  float* sa   = ws;               // B*T
  float* sb   = sa + BT;          // B*T
  float* sb2  = sb + BT;          // B*T
  float* mean = sb2 + BT;         // B*T
  float* inv  = mean + BT;        // B*T  (total ~1.25 MiB)

  k_reduce_c<<<BB * (TT / 256), 256, 0, stream>>>(x, Wa_w, Wb_w, sa, sb, sb2);
  k_scan<<<BB, 256, 0, stream>>>(g, sa, sb, sb2, mean, inv);
  k_out<<<2048, 256, 0, stream>>>(x, mean, inv, Wo_w, Wo_b, out);
}

// Round 3
// 82.525 us; speedup vs baseline: 1.1017x; 1.0073x over previous
//
#include <hip/hip_runtime.h>

constexpr int BB = 8, CC = 512, TT = 8192;
static_assert((TT & (TT - 1)) == 0 && (CC & (CC - 1)) == 0, "pow2");
constexpr int LOG_T = 13, LOG_C = 9;
constexpr float MOM = 0.05f, EPSV = 1e-6f;

typedef float v4f __attribute__((ext_vector_type(4)));

// ------- kernel 1: inline softmax + per (b,t) weighted reductions over C ----
// 512 threads = 8 waves; wave wid covers channels [wid*64, wid*64+64).
// lane l covers t = tbase + 4*l .. +3 (float4). 1 KiB/wave/channel, coalesced.
__global__ __launch_bounds__(512) void k_reduce_c(const float* __restrict__ x,
                                                  const float* __restrict__ Wa,
                                                  const float* __restrict__ Wb,
                                                  float* __restrict__ sa,
                                                  float* __restrict__ sb,
                                                  float* __restrict__ sb2) {
  __shared__ float lwa[CC];
  __shared__ float lwb[CC];
  __shared__ float xw[32];
  __shared__ float red[3][8][256];
  const int tid = threadIdx.x;
  const int lane = tid & 63;
  const int wid = tid >> 6;

  // --- softmax over C for Wa and Wb (one element per thread) ---
  float va = Wa[tid], vb = Wb[tid];
  float ma = va, mb = vb;
  #pragma unroll
  for (int off = 32; off > 0; off >>= 1) {
    ma = fmaxf(ma, __shfl_down(ma, off, 64));
    mb = fmaxf(mb, __shfl_down(mb, off, 64));
  }
  if (lane == 0) { xw[wid] = ma; xw[8 + wid] = mb; }
  __syncthreads();
  ma = xw[0]; mb = xw[8];
  #pragma unroll
  for (int w = 1; w < 8; ++w) { ma = fmaxf(ma, xw[w]); mb = fmaxf(mb, xw[8 + w]); }
  float ea = expf(va - ma), eb = expf(vb - mb);
  float sA = ea, sB = eb;
  #pragma unroll
  for (int off = 32; off > 0; off >>= 1) {
    sA += __shfl_down(sA, off, 64);
    sB += __shfl_down(sB, off, 64);
  }
  if (lane == 0) { xw[16 + wid] = sA; xw[24 + wid] = sB; }
  __syncthreads();
  sA = xw[16]; sB = xw[24];
  #pragma unroll
  for (int w = 1; w < 8; ++w) { sA += xw[16 + w]; sB += xw[24 + w]; }
  lwa[tid] = ea * (1.f / sA);
  lwb[tid] = eb * (1.f / sB);
  __syncthreads();

  // --- main weighted reduction over C ---
  const int tilesPerB = TT / 256;  // 32
  const int b = blockIdx.x / tilesPerB;
  const int tbase = (blockIdx.x % tilesPerB) * 256;
  const int t = tbase + lane * 4;
  const int cbase = wid * 64;
  const float* xp = x + ((size_t)(b * CC + cbase)) * TT + t;

  float a0=0,a1=0,a2=0,a3=0;
  float b0=0,b1=0,b2=0,b3=0;
  float q0=0,q1=0,q2=0,q3=0;
  #pragma unroll 8
  for (int cc = 0; cc < 64; ++cc) {
    float4 xv = *(const float4*)(xp + (size_t)cc * TT);
    float wac = lwa[cbase + cc];
    float wbc = lwb[cbase + cc];
    a0 = fmaf(wac, xv.x, a0); a1 = fmaf(wac, xv.y, a1);
    a2 = fmaf(wac, xv.z, a2); a3 = fmaf(wac, xv.w, a3);
    b0 = fmaf(wbc, xv.x, b0); b1 = fmaf(wbc, xv.y, b1);
    b2 = fmaf(wbc, xv.z, b2); b3 = fmaf(wbc, xv.w, b3);
    q0 = fmaf(wbc * xv.x, xv.x, q0); q1 = fmaf(wbc * xv.y, xv.y, q1);
    q2 = fmaf(wbc * xv.z, xv.z, q2); q3 = fmaf(wbc * xv.w, xv.w, q3);
  }
  const int li = lane * 4;
  red[0][wid][li+0]=a0; red[0][wid][li+1]=a1; red[0][wid][li+2]=a2; red[0][wid][li+3]=a3;
  red[1][wid][li+0]=b0; red[1][wid][li+1]=b1; red[1][wid][li+2]=b2; red[1][wid][li+3]=b3;
  red[2][wid][li+0]=q0; red[2][wid][li+1]=q1; red[2][wid][li+2]=q2; red[2][wid][li+3]=q3;
  __syncthreads();

  if (tid < 64) {
    const int o = tid * 4;
    float oa[4] = {0,0,0,0}, ob[4] = {0,0,0,0}, oq[4] = {0,0,0,0};
    #pragma unroll
    for (int w = 0; w < 8; ++w) {
      #pragma unroll
      for (int k = 0; k < 4; ++k) {
        oa[k] += red[0][w][o+k];
        ob[k] += red[1][w][o+k];
        oq[k] += red[2][w][o+k];
      }
    }
    const size_t dst = (size_t)b * TT + tbase + o;
    *(float4*)(sa  + dst) = make_float4(oa[0], oa[1], oa[2], oa[3]);
    *(float4*)(sb  + dst) = make_float4(ob[0], ob[1], ob[2], ob[3]);
    *(float4*)(sb2 + dst) = make_float4(oq[0], oq[1], oq[2], oq[3]);
  }
}

// ---------------- kernel 2: per-batch gated-EMA scans over T ----------------
// y[t] = (1-g)y[t-1] + g*in[t] is affine; compose per 8-step chunk, then
// shfl wave scan (6 rounds, no barriers) + 16-entry cross-wave fixup.
__device__ __forceinline__ float affine_scan_prev(float A, float B, int tid,
                                                  float* wAs, float* wBs) {
  const int lane = tid & 63;
  const int wid = tid >> 6;
  #pragma unroll
  for (int off = 1; off < 64; off <<= 1) {
    float pA = __shfl_up(A, off, 64);
    float pB = __shfl_up(B, off, 64);
    if (lane >= off) { B = fmaf(A, pB, B); A *= pA; }
  }
  __syncthreads();  // protect scratch from previous call
  if (lane == 63) { wAs[wid] = A; wBs[wid] = B; }
  __syncthreads();
  // carry = composition of full aggregates of waves < wid (in order)
  float cB = 0.f;
  for (int w = 0; w < wid; ++w) cB = fmaf(wAs[w], cB, wBs[w]);
  // lane-exclusive within wave = inclusive of lane-1
  float leA = __shfl_up(A, 1, 64);
  float leB = __shfl_up(B, 1, 64);
  if (lane == 0) { leA = 1.f; leB = 0.f; }
  return fmaf(leA, cB, leB);  // prefix applied to y0 = 0
}

__global__ __launch_bounds__(1024) void k_scan(const float* __restrict__ g,
                                               const float* __restrict__ sa,
                                               const float* __restrict__ sb,
                                               const float* __restrict__ sb2,
                                               float* __restrict__ mean,
                                               float* __restrict__ inv) {
  constexpr int CH = 8;  // timesteps per thread (1024 threads * 8 = 8192)
  __shared__ float wAs[16], wBs[16];
  const int tid = threadIdx.x;
  const size_t base = (size_t)blockIdx.x * TT + (size_t)tid * CH;

  // preload everything: single memory-latency exposure
  float gv[CH], av[CH], bv[CH], qv[CH];
  *(float4*)(gv)     = *(const float4*)(g   + base);
  *(float4*)(gv + 4) = *(const float4*)(g   + base + 4);
  *(float4*)(av)     = *(const float4*)(sa  + base);
  *(float4*)(av + 4) = *(const float4*)(sa  + base + 4);
  *(float4*)(bv)     = *(const float4*)(sb  + base);
  *(float4*)(bv + 4) = *(const float4*)(sb  + base + 4);
  *(float4*)(qv)     = *(const float4*)(sb2 + base);
  *(float4*)(qv + 4) = *(const float4*)(sb2 + base + 4);

  float gt[CH], pa[CH];
  float A = 1.f, Bv = 0.f;
  #pragma unroll
  for (int j = 0; j < CH; ++j) {
    float gg = gv[j] * MOM;
    gt[j] = gg;
    float p = gg * av[j];
    pa[j] = p;
    float a = 1.f - gg;
    A *= a;
    Bv = fmaf(a, Bv, p);
  }
  float m = affine_scan_prev(A, Bv, tid, wAs, wBs);

  float m4[CH];
  float A2 = 1.f, B2 = 0.f;
  #pragma unroll
  for (int j = 0; j < CH; ++j) {
    float a = 1.f - gt[j];
    m = fmaf(a, m, pa[j]);
    m4[j] = m;
    // vin = sb2 - 2*m*sb + m^2   (uses sum(wb)=1)
    float vi = fmaf(m, m, fmaf(-2.f * m, bv[j], qv[j]));
    float pv = gt[j] * vi;
    pa[j] = pv;
    A2 *= a;
    B2 = fmaf(a, B2, pv);
  }
  *(float4*)(mean + base)     = *(float4*)(m4);
  *(float4*)(mean + base + 4) = *(float4*)(m4 + 4);

  float v = affine_scan_prev(A2, B2, tid, wAs, wBs);

  float i4[CH];
  #pragma unroll
  for (int j = 0; j < CH; ++j) {
    v = fmaf(1.f - gt[j], v, pa[j]);
    i4[j] = rsqrtf(v + EPSV);
  }
  *(float4*)(inv + base)     = *(float4*)(i4);
  *(float4*)(inv + base + 4) = *(float4*)(i4 + 4);
}

// ---------------- kernel 3: pointwise output ----------------
// 8192 blocks x 256 threads x 4 float4 each == exactly B*C*T floats.
__global__ __launch_bounds__(256) void k_out(const float* __restrict__ x,
                                             const float* __restrict__ mean,
                                             const float* __restrict__ inv,
                                             const float* __restrict__ wo,
                                             const float* __restrict__ bo,
                                             float* __restrict__ out) {
  const size_t base4 = (size_t)blockIdx.x * 1024 + threadIdx.x;
  #pragma unroll
  for (int j = 0; j < 4; ++j) {
    const size_t idx = base4 + (size_t)j * 256;
    const size_t flat = idx * 4;
    const int t = (int)(flat & (TT - 1));
    const size_t rem = flat >> LOG_T;
    const int c = (int)(rem & (CC - 1));
    const int b = (int)(rem >> LOG_C);
    float4 xv = *(const float4*)(x + flat);
    const size_t mi = ((size_t)b << LOG_T) + t;
    float4 m4 = *(const float4*)(mean + mi);
    float4 i4 = *(const float4*)(inv + mi);
    const float w = wo[c], bb = bo[c];
    v4f o;
    o.x = fmaf((xv.x - m4.x) * i4.x, w, bb);
    o.y = fmaf((xv.y - m4.y) * i4.y, w, bb);
    o.z = fmaf((xv.z - m4.z) * i4.z, w, bb);
    o.w = fmaf((xv.w - m4.w) * i4.w, w, bb);
    // non-temporal: keep the out stream from evicting L3-resident x
    __builtin_nontemporal_store(o, (v4f*)(out + flat));
  }
}

extern "C" void kernel_launch(void* const* d_in, const int* in_sizes, int n_in,
                              void* d_out, int out_size, void* d_ws, size_t ws_size,
                              hipStream_t stream) {
  const float* x    = (const float*)d_in[0];  // (B, C, T)
  const float* g    = (const float*)d_in[1];  // (B, 1, T)
  const float* Wa_w = (const float*)d_in[2];  // (1, C, 1)
  const float* Wb_w = (const float*)d_in[3];  // (1, C, 1)
  const float* Wo_w = (const float*)d_in[4];  // (C, 1, 1)
  const float* Wo_b = (const float*)d_in[5];  // (C,)
  float* out = (float*)d_out;

  constexpr int BT = BB * TT;
  float* ws   = (float*)d_ws;
  float* sa   = ws;               // B*T
  float* sb   = sa + BT;          // B*T
  float* sb2  = sb + BT;          // B*T
  float* mean = sb2 + BT;         // B*T
  float* inv  = mean + BT;        // B*T  (total ~1.25 MiB)

  k_reduce_c<<<BB * (TT / 256), 512, 0, stream>>>(x, Wa_w, Wb_w, sa, sb, sb2);
  k_scan<<<BB, 1024, 0, stream>>>(g, sa, sb, sb2, mean, inv);
  k_out<<<8192, 256, 0, stream>>>(x, mean, inv, Wo_w, Wo_b, out);
}